// Round 11
// baseline (168.588 us; speedup 1.0000x reference)
//
#include <hip/hip_runtime.h>

#define EPS 1e-6f

constexpr int C    = 128;
constexpr int HW   = 65536;    // 256*256
constexpr int TILE = 128;      // pixels per block (8 waves x 16 px)
constexpr int NT   = 512;      // 8 waves

typedef __attribute__((ext_vector_type(8))) short bf16x8;
typedef __attribute__((ext_vector_type(4))) float f32x4;

__device__ __forceinline__ unsigned short f2bf(float f) {   // RNE
    unsigned u = __float_as_uint(f);
    u += 0x7fff + ((u >> 16) & 1);
    return (unsigned short)(u >> 16);
}
__device__ __forceinline__ unsigned pack2(float lo, float hi) {
    return (unsigned)f2bf(lo) | ((unsigned)f2bf(hi) << 16);
}

__global__ __launch_bounds__(NT, 4) void spnorm_kernel(
    const float* __restrict__ x, const float* __restrict__ W,
    const float* __restrict__ bias, float* __restrict__ out)
{
    // Only LDS: W as bf16, row-major [o][c], XOR-swizzled (byte ^= (o&7)<<4).
    __shared__ unsigned short wlds[C * C];                 // 32 KB

    const int tid = threadIdx.x;
    const int l   = tid & 63;
    const int wv  = tid >> 6;                              // 0..7
    const int batch = blockIdx.x >> 9;                     // 512 blocks per image
    const int hw0   = (blockIdx.x & 511) * TILE;
    const int base  = batch * (C * HW) + hw0;

    const int g   = l >> 4;                                // k-octet group 0..3
    const int p16 = l & 15;                                // pixel within wave tile
    const int pix = (wv << 4) + p16;                       // pixel within block tile

    // ---- Phase 1: x loads in MFMA-B layout: lane holds channels {32kk+8g+j} of its
    //      pixel. Per instruction: 4 x 64 B contiguous segments. Issued first (HBM). ----
    float v[32];
    {
        const float* xp = x + base + (g * 8) * HW + pix;
        #pragma unroll
        for (int kk = 0; kk < 4; ++kk)
            #pragma unroll
            for (int j = 0; j < 8; ++j)
                v[kk * 8 + j] = xp[(kk * 32 + j) * HW];
    }

    // ---- W staging: fp32 -> bf16, swizzled; overlaps with x loads in flight ----
    {
        char* wb = (char*)wlds;
        #pragma unroll
        for (int k = 0; k < 4; ++k) {
            int idx = k * NT + tid;            // 0..2047 uint4 chunks
            int o   = idx >> 4;                // W row
            int oc  = idx & 15;                // 8-channel octet
            const float* wp = W + o * C + oc * 8;
            float4 wa = *reinterpret_cast<const float4*>(wp);
            float4 wc = *reinterpret_cast<const float4*>(wp + 4);
            uint4 d;
            d.x = pack2(wa.x, wa.y);
            d.y = pack2(wa.z, wa.w);
            d.z = pack2(wc.x, wc.y);
            d.w = pack2(wc.z, wc.w);
            int byte = (o * 256 + oc * 16) ^ ((o & 7) << 4);
            *reinterpret_cast<uint4*>(wb + byte) = d;
        }
    }
    __syncthreads();                           // the ONE barrier

    // Pin v[]: forbid the compiler's reload-rematerialization (round 8/10 disease).
    #pragma unroll
    for (int i = 0; i < 32; ++i) asm volatile("" : "+v"(v[i]));

    // ---- Phase 2: in-wave stats (partials in g-lanes of same wave) ----
    float u, iv;
    {
        float s1 = 0.f, s2 = 0.f;
        #pragma unroll
        for (int i = 0; i < 32; ++i) {
            s1 += v[i];
            s2 = fmaf(v[i], v[i], s2);
        }
        s1 += __shfl_xor(s1, 16);
        s2 += __shfl_xor(s2, 16);
        s1 += __shfl_xor(s1, 32);
        s2 += __shfl_xor(s2, 32);
        u         = s1 * (1.0f / 128.0f);
        float var = fmaxf((s2 - s1 * u) * (1.0f / 127.0f), 0.0f);
        iv        = 1.0f / (sqrtf(var) + EPS);
    }

    // ---- Phase 3: normalize + pack -> B-fragments entirely in registers ----
    bf16x8 bfr[4];
    #pragma unroll
    for (int kk = 0; kk < 4; ++kk) {
        float n0 = (v[kk * 8 + 0] - u) * iv;
        float n1 = (v[kk * 8 + 1] - u) * iv;
        float n2 = (v[kk * 8 + 2] - u) * iv;
        float n3 = (v[kk * 8 + 3] - u) * iv;
        float n4 = (v[kk * 8 + 4] - u) * iv;
        float n5 = (v[kk * 8 + 5] - u) * iv;
        float n6 = (v[kk * 8 + 6] - u) * iv;
        float n7 = (v[kk * 8 + 7] - u) * iv;
        unsigned w0 = pack2(n0, n1);
        unsigned w1 = pack2(n2, n3);
        unsigned w2 = pack2(n4, n5);
        unsigned w3 = pack2(n6, n7);
        asm volatile("" : "+v"(w0), "+v"(w1), "+v"(w2), "+v"(w3));  // pin packed frags
        union { unsigned w[4]; bf16x8 f; } uu;
        uu.w[0] = w0; uu.w[1] = w1; uu.w[2] = w2; uu.w[3] = w3;
        bfr[kk] = uu.f;
    }

    // ---- Phase 4: wave-autonomous. 8 o-tiles x (A from LDS, 4 MFMA, exact-x epilogue).
    //      A-read banking: rows l&15 with ^(l&7)<<4 swizzle -> 2-way (free). ----
    {
        const char* wbc = (const char*)wlds;
        const int h    = l >> 4;
        const int aswz = (l & 7) << 4;
        const int arow0 = p16 * 256 + (h << 4);     // byte pos of (row=p16, k-octet h)
        const float* xr = x + base;
        float* outp = out + base;
        #pragma unroll
        for (int ot = 0; ot < 8; ++ot) {
            const int od = (ot << 4) + (h << 2);    // output-channel row group
            f32x4 acc = { bias[od], bias[od + 1], bias[od + 2], bias[od + 3] };
            #pragma unroll
            for (int kk = 0; kk < 4; ++kk) {
                int ab = ((ot << 12) + arow0 + kk * 64) ^ aswz;   // (ot*16+p16)*256 + ...
                bf16x8 af = *reinterpret_cast<const bf16x8*>(wbc + ab);
                acc = __builtin_amdgcn_mfma_f32_16x16x32_bf16(af, bfr[kk], acc, 0, 0, 0);
            }
            // exact fp32 x for the final multiply (L2-hot: block just read these lines)
            float xe0 = xr[(od + 0) * HW + pix];
            float xe1 = xr[(od + 1) * HW + pix];
            float xe2 = xr[(od + 2) * HW + pix];
            float xe3 = xr[(od + 3) * HW + pix];
            outp[(od + 0) * HW + pix] = xe0 * acc[0];
            outp[(od + 1) * HW + pix] = xe1 * acc[1];
            outp[(od + 2) * HW + pix] = xe2 * acc[2];
            outp[(od + 3) * HW + pix] = xe3 * acc[3];
        }
    }
}

extern "C" void kernel_launch(void* const* d_in, const int* in_sizes, int n_in,
                              void* d_out, int out_size, void* d_ws, size_t ws_size,
                              hipStream_t stream) {
    const float* x = (const float*)d_in[0];
    const float* W = (const float*)d_in[1];
    const float* b = (const float*)d_in[2];
    float* out     = (float*)d_out;

    const int nblk = 8 * HW / TILE;            // 4096 blocks
    spnorm_kernel<<<nblk, NT, 0, stream>>>(x, W, b, out);
}

// Round 12
// 120.877 us; speedup vs baseline: 1.3947x; 1.3947x over previous
//
#include <hip/hip_runtime.h>

#define EPS 1e-6f

constexpr int C    = 128;
constexpr int HW   = 65536;    // 256*256
constexpr int TILE = 128;      // pixels per block
constexpr int NT   = 512;      // 8 waves

typedef __attribute__((ext_vector_type(8))) short bf16x8;
typedef __attribute__((ext_vector_type(4))) float f32x4;

__device__ __forceinline__ unsigned short f2bf(float f) {   // RNE
    unsigned u = __float_as_uint(f);
    u += 0x7fff + ((u >> 16) & 1);
    return (unsigned short)(u >> 16);
}
__device__ __forceinline__ float bf2f(unsigned short u) {
    return __uint_as_float(((unsigned)u) << 16);
}
__device__ __forceinline__ unsigned pack2(float lo, float hi) {
    return (unsigned)f2bf(lo) | ((unsigned)f2bf(hi) << 16);
}

__global__ __launch_bounds__(NT, 4) void spnorm_kernel(
    const float* __restrict__ x, const float* __restrict__ W,
    const float* __restrict__ bias, float* __restrict__ out)
{
    // bufT[p][c]: normalized bf16, transposed, XOR-swizzled (byte ^= (p&15)<<4)
    __shared__ unsigned short bufT[C * TILE];              // 32 KB
    __shared__ float red1[4][TILE], red2[4][TILE];         // 4 KB
    __shared__ float u_s[TILE], se_s[TILE];                // 1 KB

    const int tid = threadIdx.x;
    const int l   = tid & 63;
    const int wv  = tid >> 6;
    const int batch = blockIdx.x >> 9;                     // 512 blocks per image
    const int hw0   = (blockIdx.x & 511) * TILE;
    const int base  = batch * (C * HW) + hw0;

    const int p = tid & 127;                               // pixel
    const int q = tid >> 7;                                // channel group (32 ch)

    // ---- Phase 1: x straight into registers, channel-strided, coalesced across p ----
    float v[32];
    {
        const float* xp = x + base + q * 32 * HW + p;
        #pragma unroll
        for (int i = 0; i < 32; ++i)
            v[i] = xp[i * HW];
    }

    // ---- A-fragments: W (fp32 -> bf16) from global; persistent ----
    const int arow  = (wv << 4) + (l & 15);
    const int acol0 = (l >> 4) << 3;
    bf16x8 afrag[4];
    #pragma unroll
    for (int kk = 0; kk < 4; ++kk) {
        const float* wp = W + arow * C + kk * 32 + acol0;
        float4 wa = *reinterpret_cast<const float4*>(wp);
        float4 wb = *reinterpret_cast<const float4*>(wp + 4);
        bf16x8 f;
        f[0] = (short)f2bf(wa.x); f[1] = (short)f2bf(wa.y);
        f[2] = (short)f2bf(wa.z); f[3] = (short)f2bf(wa.w);
        f[4] = (short)f2bf(wb.x); f[5] = (short)f2bf(wb.y);
        f[6] = (short)f2bf(wb.z); f[7] = (short)f2bf(wb.w);
        afrag[kk] = f;
    }
    const int od = (wv << 4) + ((l >> 4) << 2);
    const f32x4 binit = { bias[od], bias[od + 1], bias[od + 2], bias[od + 3] };

    // ---- Phase 2: partial sums -> LDS ----
    {
        float s1 = 0.f, s2 = 0.f;
        #pragma unroll
        for (int i = 0; i < 32; ++i) {
            s1 += v[i];
            s2 = fmaf(v[i], v[i], s2);
        }
        red1[q][p] = s1;
        red2[q][p] = s2;
    }

    // Pin v[]: after this point the values are opaque to the compiler, so it
    // CANNOT rematerialize them by re-loading x in phase 3 (rounds 8/10 showed
    // VGPR_Count=32 => reload-remat; the reloads inject a VMEM wait into the
    // barrier-locked critical path).
    #pragma unroll
    for (int i = 0; i < 32; ++i) asm volatile("" : "+v"(v[i]));

    __syncthreads();

    // ---- Phase 3: every thread finalizes (redundant x4, no divergence barrier),
    //      normalizes its 32 regs, writes bufT transposed+swizzled ----
    {
        float s1 = red1[0][p] + red1[1][p] + red1[2][p] + red1[3][p];
        float s2 = red2[0][p] + red2[1][p] + red2[2][p] + red2[3][p];
        float u   = s1 * (1.0f / 128.0f);
        float var = fmaxf((s2 - s1 * u) * (1.0f / 127.0f), 0.0f);
        float se  = sqrtf(var) + EPS;
        float iv  = 1.0f / se;
        if (q == 0) {                       // wave-uniform branch (tid < 128)
            u_s[p]  = u;
            se_s[p] = se;
        }
        char* tb = (char*)bufT;
        const int rowoff = p * 256;         // 128 ushort per row
        const int swz    = (p & 15) << 4;
        #pragma unroll
        for (int o8 = 0; o8 < 4; ++o8) {
            float n0 = (v[o8 * 8 + 0] - u) * iv;
            float n1 = (v[o8 * 8 + 1] - u) * iv;
            float n2 = (v[o8 * 8 + 2] - u) * iv;
            float n3 = (v[o8 * 8 + 3] - u) * iv;
            float n4 = (v[o8 * 8 + 4] - u) * iv;
            float n5 = (v[o8 * 8 + 5] - u) * iv;
            float n6 = (v[o8 * 8 + 6] - u) * iv;
            float n7 = (v[o8 * 8 + 7] - u) * iv;
            uint4 d;
            d.x = pack2(n0, n1);
            d.y = pack2(n2, n3);
            d.z = pack2(n4, n5);
            d.w = pack2(n6, n7);
            int byte = (rowoff + (q * 4 + o8) * 16) ^ swz;
            *reinterpret_cast<uint4*>(tb + byte) = d;
        }
    }
    __syncthreads();

    // ---- Phase 4: MFMA conv + epilogue. Wave wv: 16 o x 128 px (8 tiles x 4 K-steps) ----
    {
        const char* tb = (const char*)bufT;
        const int pcol = l & 15;
        const int koff = (l >> 4) << 4;
        const int swz  = pcol << 4;
        float* outp = out + base;
        #pragma unroll
        for (int pt = 0; pt < 8; ++pt) {
            const int pp     = (pt << 4) + pcol;
            const int rowoff = pp * 256;
            f32x4 acc = binit;
            #pragma unroll
            for (int kk = 0; kk < 4; ++kk) {
                int byte = (rowoff + kk * 64 + koff) ^ swz;
                bf16x8 bfrag = *reinterpret_cast<const bf16x8*>(tb + byte);
                acc = __builtin_amdgcn_mfma_f32_16x16x32_bf16(afrag[kk], bfrag, acc, 0, 0, 0);
            }
            const float uu = u_s[pp];
            const float se = se_s[pp];
            int nbyte = (rowoff + od * 2) ^ swz;
            uint2 nn = *reinterpret_cast<const uint2*>(tb + nbyte);
            float x0 = fmaf(bf2f((unsigned short)(nn.x & 0xffffu)), se, uu);
            float x1 = fmaf(bf2f((unsigned short)(nn.x >> 16)),     se, uu);
            float x2 = fmaf(bf2f((unsigned short)(nn.y & 0xffffu)), se, uu);
            float x3 = fmaf(bf2f((unsigned short)(nn.y >> 16)),     se, uu);
            outp[(od + 0) * HW + pp] = x0 * acc[0];
            outp[(od + 1) * HW + pp] = x1 * acc[1];
            outp[(od + 2) * HW + pp] = x2 * acc[2];
            outp[(od + 3) * HW + pp] = x3 * acc[3];
        }
    }
}

extern "C" void kernel_launch(void* const* d_in, const int* in_sizes, int n_in,
                              void* d_out, int out_size, void* d_ws, size_t ws_size,
                              hipStream_t stream) {
    const float* x = (const float*)d_in[0];
    const float* W = (const float*)d_in[1];
    const float* b = (const float*)d_in[2];
    float* out     = (float*)d_out;

    const int nblk = 8 * HW / TILE;            // 4096 blocks
    spnorm_kernel<<<nblk, NT, 0, stream>>>(x, W, b, out);
}